// Round 15
// baseline (441.580 us; speedup 1.0000x reference)
//
#include <hip/hip_runtime.h>
#include <hip/hip_bf16.h>

// N=100000 nodes, D=64 feat, H=256 hidden, E=1000000 edges per relation.
#define N_NODES 100000
#define DIM 64
#define HID 256
#define E_EDGES 1000000
#define TWO_N (2 * N_NODES)
#define MLP_ROWBLOCKS (TWO_N / 64)                   // 3125 blocks of 64 z-rows

// Binned aggregation.
#define TILE 60                                      // nodes per bin
#define NBINS 1667                                   // ceil(100000/60)
#define CAP 800                                      // mean 600, sd ~24.5 -> +8.2 sd
#define EPB 4096                                     // edges per bin_fill block
#define FILL_BLOCKS 245                              // ceil(E/EPB)

// Src-chunk keys + CHUNK-OUTER gather: R4 proved chunk-outer + co-resident grid
// cuts FETCH 186->62MB (phase-synced 2MB featb window ~= L2). R9 proved flat
// loops revert it (182MB): the LOOP STRUCTURE, not data order, enforces phase.
#define NCH 8                                        // chunk = src >> 14
#define KEYS (TILE * NCH)                            // 480 sort keys

// Fused prep kernel block ranges.
#define PACKF_BLOCKS 782                             // ceil(1.6M us4 / 2048)
#define PACKW1_BLOCKS 32                             // 16384 / 512
#define PREP_BLOCKS (2 * FILL_BLOCKS + PACKF_BLOCKS + PACKW1_BLOCKS)

typedef short short8 __attribute__((ext_vector_type(8)));   // 8 bf16 (4 VGPRs)
typedef float f32x4 __attribute__((ext_vector_type(4)));
typedef unsigned short us4 __attribute__((ext_vector_type(4)));
typedef unsigned short us8 __attribute__((ext_vector_type(8)));

__device__ __forceinline__ float tanh_fast(float x) {
    x = fminf(fmaxf(x, -15.0f), 15.0f);
    float e = __expf(2.0f * x);
    return (e - 1.0f) / (e + 1.0f);
}

__device__ __forceinline__ unsigned short f2bf(float x) {   // RNE f32->bf16
    unsigned u = __float_as_uint(x);
    u = u + 0x7FFFu + ((u >> 16) & 1u);
    return (unsigned short)(u >> 16);
}

__device__ __forceinline__ float bf2f(unsigned short u) {
    return __uint_as_float(((unsigned)u) << 16);
}

// ---------- Fused prep: bin_fill (blocks 0..489) | pack_feat | pack_w1 ----------
__global__ void __launch_bounds__(512) prep_kernel(
        const int* __restrict__ gs, const int* __restrict__ gd,
        const int* __restrict__ ts, const int* __restrict__ td,
        const float* __restrict__ tw,
        int* __restrict__ gcount,
        int* __restrict__ gbin, int2* __restrict__ tbin,
        const float* __restrict__ feat, unsigned short* __restrict__ fb,
        const float* __restrict__ W1, unsigned short* __restrict__ W1p) {
    __shared__ int   hist[NBINS];
    __shared__ int   adjS[NBINS];                    // gbase - lbase per bin
    __shared__ int   curS[NBINS];
    __shared__ int   pS[EPB];                        // sorted payload (src|dloc<<20)
    __shared__ float w2S[EPB];                       // sorted weights (trans only)
    __shared__ unsigned short binS[EPB];             // bin of sorted slot
    __shared__ int   wsumS[8];                       // per-wave chunk sums
    __shared__ int   wpreS[8];                       // inclusive wave prefix

    int t = threadIdx.x;
    int blk = blockIdx.x;

    if (blk >= 2 * FILL_BLOCKS) {
        int pb = blk - 2 * FILL_BLOCKS;
        if (pb < PACKF_BLOCKS) {
            // pack_feat: float4 -> us4, 4 per thread.
            #pragma unroll
            for (int j = 0; j < 4; ++j) {
                int i = pb * 2048 + j * 512 + t;
                if (i < N_NODES * DIM / 4) {
                    float4 v = ((const float4*)feat)[i];
                    us4 o;
                    o[0] = f2bf(v.x); o[1] = f2bf(v.y); o[2] = f2bf(v.z); o[3] = f2bf(v.w);
                    ((us4*)fb)[i] = o;
                }
            }
        } else {
            // pack_w1: B-fragment order.
            int i = (pb - PACKF_BLOCKS) * 512 + t;   // 0..16383
            int j = i & 7;
            int r = i >> 3;
            int nidx = r & 15; r >>= 4;
            int q = r & 3; r >>= 2;
            int khalf = r & 1;
            int n = r >> 1;
            int k = 32 * khalf + 8 * q + j;
            int c = 16 * n + nidx;
            W1p[i] = f2bf(W1[k * HID + c]);
        }
        return;
    }

    // ---- bin_fill path ----
    int lane = t & 63, wv = t >> 6;
    int rel = (blk >= FILL_BLOCKS) ? 1 : 0;
    int e0 = (rel ? blk - FILL_BLOCKS : blk) * EPB;
    const int* dstp = rel ? td : gd;
    const int* srcp = rel ? ts : gs;

    for (int i = t; i < NBINS; i += 512) hist[i] = 0;
    __syncthreads();

    // Load 8 edges per thread into registers (int4 reads), histogram.
    int d_[8], s_[8];
    float w_[8];
    #pragma unroll
    for (int j = 0; j < 2; ++j) {
        int idx = e0 + j * 2048 + 4 * t;
        if (idx + 3 < E_EDGES) {
            int4 dv = *(const int4*)&dstp[idx];
            int4 sv = *(const int4*)&srcp[idx];
            d_[4*j+0] = dv.x; d_[4*j+1] = dv.y; d_[4*j+2] = dv.z; d_[4*j+3] = dv.w;
            s_[4*j+0] = sv.x; s_[4*j+1] = sv.y; s_[4*j+2] = sv.z; s_[4*j+3] = sv.w;
            if (rel) {
                float4 wvv = *(const float4*)&tw[idx];
                w_[4*j+0] = wvv.x; w_[4*j+1] = wvv.y; w_[4*j+2] = wvv.z; w_[4*j+3] = wvv.w;
            }
        } else {
            #pragma unroll
            for (int i2 = 0; i2 < 4; ++i2) {
                bool ok = (idx + i2 < E_EDGES);
                d_[4*j+i2] = ok ? dstp[idx + i2] : -1;
                s_[4*j+i2] = ok ? srcp[idx + i2] : 0;
                w_[4*j+i2] = (ok && rel) ? tw[idx + i2] : 0.0f;
            }
        }
    }
    #pragma unroll
    for (int i = 0; i < 8; ++i)
        if (d_[i] >= 0) atomicAdd(&hist[d_[i] / TILE], 1);
    __syncthreads();

    // Exclusive scan over NBINS via wave-shuffle scan; reserve global space per bin.
    int carry = 0;
    for (int cb = 0; cb < NBINS; cb += 512) {
        int i = cb + t;
        int c = (i < NBINS) ? hist[i] : 0;
        int v = c;
        #pragma unroll
        for (int off = 1; off < 64; off <<= 1) {
            int u = __shfl_up(v, off);
            if (lane >= off) v += u;
        }
        if (lane == 63) wsumS[wv] = v;
        __syncthreads();
        if (t == 0) {
            int s = 0;
            #pragma unroll
            for (int w = 0; w < 8; ++w) { s += wsumS[w]; wpreS[w] = s; }
        }
        __syncthreads();
        int woff = (wv == 0) ? 0 : wpreS[wv - 1];
        if (i < NBINS) {
            int lb = carry + woff + v - c;            // exclusive local base
            curS[i] = lb;
            int gb = (c > 0) ? (i * CAP + atomicAdd(&gcount[rel * NBINS + i], c)) : 0;
            adjS[i] = gb - lb;
        }
        carry += wpreS[7];
        __syncthreads();                              // wsumS reuse next chunk
    }
    __syncthreads();

    // Place into sorted LDS order.
    #pragma unroll
    for (int i = 0; i < 8; ++i) {
        int d = d_[i];
        if (d < 0) continue;
        int bin = d / TILE;
        int pos = atomicAdd(&curS[bin], 1);
        pS[pos] = s_[i] | ((d - bin * TILE) << 20);
        binS[pos] = (unsigned short)bin;
        if (rel) w2S[pos] = w_[i];
    }
    __syncthreads();

    // Coalesced copy-out: consecutive slots in a bin -> consecutive global addrs.
    int nV = min(EPB, E_EDGES - e0);
    if (!rel) {
        for (int i = t; i < nV; i += 512) {
            int b = binS[i];
            int gi = adjS[b] + i;
            if (gi < (b + 1) * CAP)                          // overflow guard (P~0)
                gbin[gi] = pS[i];
        }
    } else {
        for (int i = t; i < nV; i += 512) {
            int b = binS[i];
            int gi = adjS[b] + i;
            if (gi < (b + 1) * CAP)
                tbin[gi] = make_int2(pS[i], __float_as_int(w2S[i]));
        }
    }
}

// Exclusive scan over KEYS counters; writes kb[0..KEYS] (kb[KEYS]=nE) and cur=kb.
__device__ __forceinline__ void scan_keys(int* hist, int* kb, int* cur,
                                          int* wsA, int* wpA, int nE,
                                          int t, int lane, int wave) {
    int carry = 0;
    for (int cb = 0; cb < KEYS; cb += 256) {
        int i = cb + t;
        int c = (i < KEYS) ? hist[i] : 0;
        int v = c;
        #pragma unroll
        for (int off = 1; off < 64; off <<= 1) {
            int u = __shfl_up(v, off);
            if (lane >= off) v += u;
        }
        if (lane == 63) wsA[wave] = v;
        __syncthreads();
        if (t == 0) {
            int s = 0;
            #pragma unroll
            for (int w = 0; w < 4; ++w) { s += wsA[w]; wpA[w] = s; }
        }
        __syncthreads();
        int woff = (wave == 0) ? 0 : wpA[wave - 1];
        if (i < KEYS) {
            int lb = carry + woff + v - c;
            kb[i] = lb;
            cur[i] = lb;
        }
        carry += wpA[3];
        __syncthreads();
    }
    if (t == 0) kb[KEYS] = nE;
    __syncthreads();
}

// ---------- Phase B: one block per bin, BOTH relations, chunk-outer gather ----------
// Chunk-outer loop (R4's proven byte mechanism: FETCH 62MB) with a BRANCHLESS
// 4-way interleave of the per-chunk segments {geoA, geoB, transA, transB}:
// every round issues 4 unconditional 16B loads (predicated by gate-FMA / w=0),
// fixing R4's 1-load-in-flight serialization (1.56 TB/s issue-bound).
__global__ void __launch_bounds__(256, 7) aggregate_kernel(
        const unsigned short* __restrict__ featb,
        const int* __restrict__ gbin, const int2* __restrict__ tbin,
        const int* __restrict__ gcount,
        unsigned short* __restrict__ zb) {
    __shared__ int   srcG[CAP];          // 3.2 KB geo sorted src
    __shared__ int   srcT[CAP];          // 3.2 KB trans sorted src
    __shared__ float wT[CAP];            // 3.2 KB trans sorted weights
    __shared__ int   kbG[KEYS + 1];      // 1.92 KB segment bounds
    __shared__ int   kbT[KEYS + 1];
    __shared__ int   histK[KEYS];
    __shared__ int   curK[KEYS];
    __shared__ int   wsA[4];
    __shared__ int   wpA[4];

    int bin = blockIdx.x;
    int node0 = bin * TILE;
    int nNodes = min(TILE, N_NODES - node0);
    int t = threadIdx.x, lane = t & 63, wave = t >> 6;   // 4 waves
    int g = wave * 8 + (lane >> 3);                      // group 0..31
    int co = (lane & 7) * 8;                             // column offset (8 bf16)

    int nEg = min(gcount[bin], CAP);
    int nEt = min(gcount[NBINS + bin], CAP);
    const int*  bpg = gbin + (size_t)bin * CAP;
    const int2* bpt = tbin + (size_t)bin * CAP;

    // ---- sort geo by (dloc*8 | src>>14) ----
    for (int i = t; i < KEYS; i += 256) histK[i] = 0;
    __syncthreads();
    for (int i = t; i < nEg; i += 256) {
        int p = bpg[i];
        atomicAdd(&histK[((p >> 20) << 3) | ((p & 0xFFFFF) >> 14)], 1);
    }
    __syncthreads();
    scan_keys(histK, kbG, curK, wsA, wpA, nEg, t, lane, wave);
    for (int i = t; i < nEg; i += 256) {
        int p = bpg[i];
        int key = ((p >> 20) << 3) | ((p & 0xFFFFF) >> 14);
        int pos = atomicAdd(&curK[key], 1);
        srcG[pos] = p & 0xFFFFF;
    }
    __syncthreads();

    // ---- sort trans (reuse histK/curK) ----
    for (int i = t; i < KEYS; i += 256) histK[i] = 0;
    __syncthreads();
    for (int i = t; i < nEt; i += 256) {
        int p = bpt[i].x;
        atomicAdd(&histK[((p >> 20) << 3) | ((p & 0xFFFFF) >> 14)], 1);
    }
    __syncthreads();
    scan_keys(histK, kbT, curK, wsA, wpA, nEt, t, lane, wave);
    for (int i = t; i < nEt; i += 256) {
        int2 p = bpt[i];
        int key = ((p.x >> 20) << 3) | ((p.x & 0xFFFFF) >> 14);
        int pos = atomicAdd(&curK[key], 1);
        srcT[pos] = p.x & 0xFFFFF;
        wT[pos]   = __int_as_float(p.y);
    }
    __syncthreads();

    // ---- chunk-outer gather, branchless 4-way interleaved segments ----
    float aGA[8] = {0.f,0.f,0.f,0.f,0.f,0.f,0.f,0.f};
    float aGB[8] = {0.f,0.f,0.f,0.f,0.f,0.f,0.f,0.f};
    float aTA[8] = {0.f,0.f,0.f,0.f,0.f,0.f,0.f,0.f};
    float aTB[8] = {0.f,0.f,0.f,0.f,0.f,0.f,0.f,0.f};
    int nA = g, nB = g + 32;
    bool actA = (nA < nNodes);
    bool hasB = (nB < nNodes);

    for (int c = 0; c < NCH; ++c) {
        int kA = 0, eA = 0, kB = 0, eB = 0, kT = 0, eT = 0, kU = 0, eU = 0;
        if (actA) {
            kA = kbG[nA * NCH + c]; eA = kbG[nA * NCH + c + 1];
            kT = kbT[nA * NCH + c]; eT = kbT[nA * NCH + c + 1];
        }
        if (hasB) {
            kB = kbG[nB * NCH + c]; eB = kbG[nB * NCH + c + 1];
            kU = kbT[nB * NCH + c]; eU = kbT[nB * NCH + c + 1];
        }
        while ((kA < eA) | (kB < eB) | (kT < eT) | (kU < eU)) {
            bool a = kA < eA, b = kB < eB, t2 = kT < eT, u = kU < eU;
            int sA = srcG[a  ? kA : 0];
            int sB = srcG[b  ? kB : 0];
            int sT = srcT[t2 ? kT : 0];
            int sU = srcT[u  ? kU : 0];
            float gAf = a ? 1.0f : 0.0f;
            float gBf = b ? 1.0f : 0.0f;
            float wt  = t2 ? wT[kT] : 0.0f;
            float wu  = u  ? wT[kU] : 0.0f;
            us8 rA = *(const us8*)&featb[(size_t)sA * DIM + co];
            us8 rB = *(const us8*)&featb[(size_t)sB * DIM + co];
            us8 rT = *(const us8*)&featb[(size_t)sT * DIM + co];
            us8 rU = *(const us8*)&featb[(size_t)sU * DIM + co];
            #pragma unroll
            for (int j = 0; j < 8; ++j) {
                aGA[j] += bf2f(rA[j]) * gAf;
                aGB[j] += bf2f(rB[j]) * gBf;
                aTA[j] += bf2f(rT[j]) * wt;
                aTB[j] += bf2f(rU[j]) * wu;
            }
            kA += a; kB += b; kT += t2; kU += u;
        }
    }

    // ---- write zb rows ----
    if (actA) {
        int degA = kbG[(nA + 1) * NCH] - kbG[nA * NCH];
        float sc = 1.0f / fmaxf((float)degA, 1.0f);          // geo -> mean
        us8 og, ot;
        #pragma unroll
        for (int j = 0; j < 8; ++j) { og[j] = f2bf(aGA[j] * sc); ot[j] = f2bf(aTA[j]); }
        *(us8*)&zb[(size_t)(node0 + nA) * DIM + co] = og;
        *(us8*)&zb[(size_t)(N_NODES + node0 + nA) * DIM + co] = ot;
    }
    if (hasB) {
        int degB = kbG[(nB + 1) * NCH] - kbG[nB * NCH];
        float sc = 1.0f / fmaxf((float)degB, 1.0f);
        us8 og, ot;
        #pragma unroll
        for (int j = 0; j < 8; ++j) { og[j] = f2bf(aGB[j] * sc); ot[j] = f2bf(aTB[j]); }
        *(us8*)&zb[(size_t)(node0 + nB) * DIM + co] = og;
        *(us8*)&zb[(size_t)(N_NODES + node0 + nB) * DIM + co] = ot;
    }
}

// ---------- Semantic-attention MLP via bf16 MFMA; A-frags loaded directly from zb ----
__global__ void __launch_bounds__(256) mlp_mfma_kernel(
        const unsigned short* __restrict__ zb,
        const unsigned short* __restrict__ W1p,
        const float* __restrict__ bias1, const float* __restrict__ W2,
        float* __restrict__ partials) {
    __shared__ float wred[4][2];
    int t = threadIdx.x, lane = t & 63, wave = t >> 6;
    int m = lane & 15, q = lane >> 4;
    int base = blockIdx.x * 64 + wave * 16;
    int R = base + m;

    const unsigned short* rowp = zb + (size_t)R * DIM;
    short8 a0 = *(const short8*)(rowp + q * 8);          // k = q*8..q*8+7
    short8 a1 = *(const short8*)(rowp + 32 + q * 8);     // k = 32+q*8..

    float c0 = 0.0f, c1 = 0.0f;
    const short8* W1v = (const short8*)W1p;   // 2048 frags of 8 bf16

    #pragma unroll 4
    for (int n = 0; n < 16; ++n) {
        short8 b0 = W1v[(n * 2 + 0) * 64 + lane];
        short8 bK = W1v[(n * 2 + 1) * 64 + lane];
        f32x4 acc = {0.0f, 0.0f, 0.0f, 0.0f};
        acc = __builtin_amdgcn_mfma_f32_16x16x32_bf16(a0, b0, acc, 0, 0, 0);
        acc = __builtin_amdgcn_mfma_f32_16x16x32_bf16(a1, bK, acc, 0, 0, 0);
        int col = 16 * n + m;                 // C/D: col=lane&15, row=q*4+reg
        float bj = bias1[col];
        float w2 = W2[col];
        #pragma unroll
        for (int reg = 0; reg < 4; ++reg) {
            int Rr = base + q * 4 + reg;
            float h = tanh_fast(acc[reg] + bj);
            float contrib = h * w2;
            if (Rr < N_NODES) c0 += contrib; else c1 += contrib;
        }
    }

    #pragma unroll
    for (int off = 32; off > 0; off >>= 1) {
        c0 += __shfl_down(c0, off);
        c1 += __shfl_down(c1, off);
    }
    if (lane == 0) { wred[wave][0] = c0; wred[wave][1] = c1; }
    __syncthreads();
    if (t == 0) {
        partials[blockIdx.x * 2 + 0] = wred[0][0] + wred[1][0] + wred[2][0] + wred[3][0];
        partials[blockIdx.x * 2 + 1] = wred[0][1] + wred[1][1] + wred[2][1] + wred[3][1];
    }
}

// ---------- combine (+ fused beta): out = beta0*geo_mean + beta1*trans ----------
__global__ void __launch_bounds__(256) combine_kernel(
        const unsigned short* __restrict__ zb,
        const float* __restrict__ partials,
        float* __restrict__ out) {
    __shared__ float wred[4][2];
    __shared__ float bS[2];
    int t = threadIdx.x, lane = t & 63, wv = t >> 6;

    // Redundant per-block beta reduction (partials are L2-resident, 25 KB).
    float c0 = 0.0f, c1 = 0.0f;
    for (int i = t; i < MLP_ROWBLOCKS; i += 256) {
        c0 += partials[i * 2 + 0];
        c1 += partials[i * 2 + 1];
    }
    #pragma unroll
    for (int off = 32; off > 0; off >>= 1) {
        c0 += __shfl_down(c0, off);
        c1 += __shfl_down(c1, off);
    }
    if (lane == 0) { wred[wv][0] = c0; wred[wv][1] = c1; }
    __syncthreads();
    if (t == 0) {
        float s0 = (wred[0][0] + wred[1][0] + wred[2][0] + wred[3][0]) / (float)N_NODES;
        float s1 = (wred[0][1] + wred[1][1] + wred[2][1] + wred[3][1]) / (float)N_NODES;
        float m = fmaxf(s0, s1);
        float e0 = __expf(s0 - m), e1 = __expf(s1 - m);
        float inv = 1.0f / (e0 + e1);
        bS[0] = e0 * inv;
        bS[1] = e1 * inv;
    }
    __syncthreads();
    float b0 = bS[0];
    float b1 = bS[1];

    int gid = blockIdx.x * 256 + t;             // 8 elements per thread
    uint4 g = *(const uint4*)&zb[(size_t)gid * 8];
    uint4 tr = *(const uint4*)&zb[(size_t)N_NODES * DIM + (size_t)gid * 8];
    float4 o0, o1;
    o0.x = b0 * __uint_as_float(g.x << 16) + b1 * __uint_as_float(tr.x << 16);
    o0.y = b0 * __uint_as_float(g.x & 0xFFFF0000u) + b1 * __uint_as_float(tr.x & 0xFFFF0000u);
    o0.z = b0 * __uint_as_float(g.y << 16) + b1 * __uint_as_float(tr.y << 16);
    o0.w = b0 * __uint_as_float(g.y & 0xFFFF0000u) + b1 * __uint_as_float(tr.y & 0xFFFF0000u);
    o1.x = b0 * __uint_as_float(g.z << 16) + b1 * __uint_as_float(tr.z << 16);
    o1.y = b0 * __uint_as_float(g.z & 0xFFFF0000u) + b1 * __uint_as_float(tr.z & 0xFFFF0000u);
    o1.z = b0 * __uint_as_float(g.w << 16) + b1 * __uint_as_float(tr.w << 16);
    o1.w = b0 * __uint_as_float(g.w & 0xFFFF0000u) + b1 * __uint_as_float(tr.w & 0xFFFF0000u);
    *(float4*)&out[(size_t)gid * 8] = o0;
    *(float4*)&out[(size_t)gid * 8 + 4] = o1;
}

extern "C" void kernel_launch(void* const* d_in, const int* in_sizes, int n_in,
                              void* d_out, int out_size, void* d_ws, size_t ws_size,
                              hipStream_t stream) {
    const float* loc_feat = (const float*)d_in[0];
    const int* geo_src    = (const int*)d_in[1];
    const int* geo_dst    = (const int*)d_in[2];
    const int* trans_src  = (const int*)d_in[3];
    const int* trans_dst  = (const int*)d_in[4];
    const float* trans_w  = (const float*)d_in[5];
    const float* W1       = (const float*)d_in[6];
    const float* b1       = (const float*)d_in[7];
    const float* W2       = (const float*)d_in[8];
    float* out = (float*)d_out;

    // ws layout (4B units): [gcount 2*NBINS][gbin NBINS*CAP int][tbin NBINS*CAP int2]
    //   [partials 2*3125][beta 2 (unused)][W1p 16384 u16][featb N*64 u16][zb 2N*64 u16]
    int*   gcount   = (int*)d_ws;
    int*   gbin     = gcount + 2 * NBINS;
    int2*  tbin     = (int2*)(gbin + (size_t)NBINS * CAP);
    float* partials = (float*)(tbin + (size_t)NBINS * CAP);
    float* beta     = partials + 2 * MLP_ROWBLOCKS;
    unsigned short* W1p   = (unsigned short*)(beta + 2);
    unsigned short* featb = W1p + 16384;
    unsigned short* zb    = featb + (size_t)N_NODES * DIM;

    hipMemsetAsync(gcount, 0, 2 * NBINS * sizeof(int), stream);

    prep_kernel<<<PREP_BLOCKS, 512, 0, stream>>>(geo_src, geo_dst, trans_src,
                                                 trans_dst, trans_w,
                                                 gcount, gbin, tbin,
                                                 loc_feat, featb, W1, W1p);
    aggregate_kernel<<<NBINS, 256, 0, stream>>>(featb, gbin, tbin, gcount, zb);
    mlp_mfma_kernel<<<MLP_ROWBLOCKS, 256, 0, stream>>>(zb, W1p, b1, W2, partials);
    combine_kernel<<<(N_NODES * DIM / 8) / 256, 256, 0, stream>>>(zb, partials, out);
}

// Round 18
// 228.172 us; speedup vs baseline: 1.9353x; 1.9353x over previous
//
#include <hip/hip_runtime.h>
#include <hip/hip_bf16.h>

// N=100000 nodes, D=64 feat, H=256 hidden, E=1000000 edges per relation.
#define N_NODES 100000
#define DIM 64
#define HID 256
#define E_EDGES 1000000
#define TWO_N (2 * N_NODES)
#define MLP_ROWBLOCKS (TWO_N / 64)                   // 3125 blocks of 64 z-rows

// Binned aggregation.
#define TILE 60                                      // nodes per bin
#define NBINS 1667                                   // ceil(100000/60)
#define CAP 800                                      // mean 600, sd ~24.5 -> +8.2 sd
#define EPB 4096                                     // edges per bin_fill block
#define FILL_BLOCKS 245                              // ceil(E/EPB)

// Src-chunk keys + CHUNK-OUTER gather: R4 proved chunk-outer + co-resident grid
// cuts FETCH 186->62MB. R9 proved flat loops revert it (182MB). R15 proved a
// 4-way interleave (32 live acc floats) SPILLS to scratch (WRITE 25->501MB,
// 271us): only the actively-updated acc set stays in VGPRs; the rest must park
// in AGPRs. Hence 2-WAY interleave: per chunk, loop A merges {geoA,transA}
// (16 floats live), then loop B merges {geoB,transB}.
#define NCH 8                                        // chunk = src >> 14
#define KEYS (TILE * NCH)                            // 480 sort keys

// Fused prep kernel block ranges.
#define PACKF_BLOCKS 782                             // ceil(1.6M us4 / 2048)
#define PACKW1_BLOCKS 32                             // 16384 / 512
#define PREP_BLOCKS (2 * FILL_BLOCKS + PACKF_BLOCKS + PACKW1_BLOCKS)

typedef short short8 __attribute__((ext_vector_type(8)));   // 8 bf16 (4 VGPRs)
typedef float f32x4 __attribute__((ext_vector_type(4)));
typedef unsigned short us4 __attribute__((ext_vector_type(4)));
typedef unsigned short us8 __attribute__((ext_vector_type(8)));

__device__ __forceinline__ float tanh_fast(float x) {
    x = fminf(fmaxf(x, -15.0f), 15.0f);
    float e = __expf(2.0f * x);
    return (e - 1.0f) / (e + 1.0f);
}

__device__ __forceinline__ unsigned short f2bf(float x) {   // RNE f32->bf16
    unsigned u = __float_as_uint(x);
    u = u + 0x7FFFu + ((u >> 16) & 1u);
    return (unsigned short)(u >> 16);
}

__device__ __forceinline__ float bf2f(unsigned short u) {
    return __uint_as_float(((unsigned)u) << 16);
}

// ---------- Fused prep: bin_fill (blocks 0..489) | pack_feat | pack_w1 ----------
__global__ void __launch_bounds__(512) prep_kernel(
        const int* __restrict__ gs, const int* __restrict__ gd,
        const int* __restrict__ ts, const int* __restrict__ td,
        const float* __restrict__ tw,
        int* __restrict__ gcount,
        int* __restrict__ gbin, int2* __restrict__ tbin,
        const float* __restrict__ feat, unsigned short* __restrict__ fb,
        const float* __restrict__ W1, unsigned short* __restrict__ W1p) {
    __shared__ int   hist[NBINS];
    __shared__ int   adjS[NBINS];                    // gbase - lbase per bin
    __shared__ int   curS[NBINS];
    __shared__ int   pS[EPB];                        // sorted payload (src|dloc<<20)
    __shared__ float w2S[EPB];                       // sorted weights (trans only)
    __shared__ unsigned short binS[EPB];             // bin of sorted slot
    __shared__ int   wsumS[8];                       // per-wave chunk sums
    __shared__ int   wpreS[8];                       // inclusive wave prefix

    int t = threadIdx.x;
    int blk = blockIdx.x;

    if (blk >= 2 * FILL_BLOCKS) {
        int pb = blk - 2 * FILL_BLOCKS;
        if (pb < PACKF_BLOCKS) {
            // pack_feat: float4 -> us4, 4 per thread.
            #pragma unroll
            for (int j = 0; j < 4; ++j) {
                int i = pb * 2048 + j * 512 + t;
                if (i < N_NODES * DIM / 4) {
                    float4 v = ((const float4*)feat)[i];
                    us4 o;
                    o[0] = f2bf(v.x); o[1] = f2bf(v.y); o[2] = f2bf(v.z); o[3] = f2bf(v.w);
                    ((us4*)fb)[i] = o;
                }
            }
        } else {
            // pack_w1: B-fragment order.
            int i = (pb - PACKF_BLOCKS) * 512 + t;   // 0..16383
            int j = i & 7;
            int r = i >> 3;
            int nidx = r & 15; r >>= 4;
            int q = r & 3; r >>= 2;
            int khalf = r & 1;
            int n = r >> 1;
            int k = 32 * khalf + 8 * q + j;
            int c = 16 * n + nidx;
            W1p[i] = f2bf(W1[k * HID + c]);
        }
        return;
    }

    // ---- bin_fill path ----
    int lane = t & 63, wv = t >> 6;
    int rel = (blk >= FILL_BLOCKS) ? 1 : 0;
    int e0 = (rel ? blk - FILL_BLOCKS : blk) * EPB;
    const int* dstp = rel ? td : gd;
    const int* srcp = rel ? ts : gs;

    for (int i = t; i < NBINS; i += 512) hist[i] = 0;
    __syncthreads();

    // Load 8 edges per thread into registers (int4 reads), histogram.
    int d_[8], s_[8];
    float w_[8];
    #pragma unroll
    for (int j = 0; j < 2; ++j) {
        int idx = e0 + j * 2048 + 4 * t;
        if (idx + 3 < E_EDGES) {
            int4 dv = *(const int4*)&dstp[idx];
            int4 sv = *(const int4*)&srcp[idx];
            d_[4*j+0] = dv.x; d_[4*j+1] = dv.y; d_[4*j+2] = dv.z; d_[4*j+3] = dv.w;
            s_[4*j+0] = sv.x; s_[4*j+1] = sv.y; s_[4*j+2] = sv.z; s_[4*j+3] = sv.w;
            if (rel) {
                float4 wvv = *(const float4*)&tw[idx];
                w_[4*j+0] = wvv.x; w_[4*j+1] = wvv.y; w_[4*j+2] = wvv.z; w_[4*j+3] = wvv.w;
            }
        } else {
            #pragma unroll
            for (int i2 = 0; i2 < 4; ++i2) {
                bool ok = (idx + i2 < E_EDGES);
                d_[4*j+i2] = ok ? dstp[idx + i2] : -1;
                s_[4*j+i2] = ok ? srcp[idx + i2] : 0;
                w_[4*j+i2] = (ok && rel) ? tw[idx + i2] : 0.0f;
            }
        }
    }
    #pragma unroll
    for (int i = 0; i < 8; ++i)
        if (d_[i] >= 0) atomicAdd(&hist[d_[i] / TILE], 1);
    __syncthreads();

    // Exclusive scan over NBINS via wave-shuffle scan; reserve global space per bin.
    int carry = 0;
    for (int cb = 0; cb < NBINS; cb += 512) {
        int i = cb + t;
        int c = (i < NBINS) ? hist[i] : 0;
        int v = c;
        #pragma unroll
        for (int off = 1; off < 64; off <<= 1) {
            int u = __shfl_up(v, off);
            if (lane >= off) v += u;
        }
        if (lane == 63) wsumS[wv] = v;
        __syncthreads();
        if (t == 0) {
            int s = 0;
            #pragma unroll
            for (int w = 0; w < 8; ++w) { s += wsumS[w]; wpreS[w] = s; }
        }
        __syncthreads();
        int woff = (wv == 0) ? 0 : wpreS[wv - 1];
        if (i < NBINS) {
            int lb = carry + woff + v - c;            // exclusive local base
            curS[i] = lb;
            int gb = (c > 0) ? (i * CAP + atomicAdd(&gcount[rel * NBINS + i], c)) : 0;
            adjS[i] = gb - lb;
        }
        carry += wpreS[7];
        __syncthreads();                              // wsumS reuse next chunk
    }
    __syncthreads();

    // Place into sorted LDS order.
    #pragma unroll
    for (int i = 0; i < 8; ++i) {
        int d = d_[i];
        if (d < 0) continue;
        int bin = d / TILE;
        int pos = atomicAdd(&curS[bin], 1);
        pS[pos] = s_[i] | ((d - bin * TILE) << 20);
        binS[pos] = (unsigned short)bin;
        if (rel) w2S[pos] = w_[i];
    }
    __syncthreads();

    // Coalesced copy-out: consecutive slots in a bin -> consecutive global addrs.
    int nV = min(EPB, E_EDGES - e0);
    if (!rel) {
        for (int i = t; i < nV; i += 512) {
            int b = binS[i];
            int gi = adjS[b] + i;
            if (gi < (b + 1) * CAP)                          // overflow guard (P~0)
                gbin[gi] = pS[i];
        }
    } else {
        for (int i = t; i < nV; i += 512) {
            int b = binS[i];
            int gi = adjS[b] + i;
            if (gi < (b + 1) * CAP)
                tbin[gi] = make_int2(pS[i], __float_as_int(w2S[i]));
        }
    }
}

// Exclusive scan over KEYS counters; writes kb[0..KEYS] (kb[KEYS]=nE) and cur=kb.
__device__ __forceinline__ void scan_keys(int* hist, int* kb, int* cur,
                                          int* wsA, int* wpA, int nE,
                                          int t, int lane, int wave) {
    int carry = 0;
    for (int cb = 0; cb < KEYS; cb += 256) {
        int i = cb + t;
        int c = (i < KEYS) ? hist[i] : 0;
        int v = c;
        #pragma unroll
        for (int off = 1; off < 64; off <<= 1) {
            int u = __shfl_up(v, off);
            if (lane >= off) v += u;
        }
        if (lane == 63) wsA[wave] = v;
        __syncthreads();
        if (t == 0) {
            int s = 0;
            #pragma unroll
            for (int w = 0; w < 4; ++w) { s += wsA[w]; wpA[w] = s; }
        }
        __syncthreads();
        int woff = (wave == 0) ? 0 : wpA[wave - 1];
        if (i < KEYS) {
            int lb = carry + woff + v - c;
            kb[i] = lb;
            cur[i] = lb;
        }
        carry += wpA[3];
        __syncthreads();
    }
    if (t == 0) kb[KEYS] = nE;
    __syncthreads();
}

// ---------- Phase B: one block per bin, BOTH relations, chunk-outer gather ----------
// Chunk-outer loop (byte mechanism) with 2-WAY merged segments per node:
// loop A merges {geoA, transA} (2 predicated loads/round, 16 acc floats live),
// then loop B merges {geoB, transB}. The inactive node's accumulators park in
// AGPRs (R4 behavior), avoiding R15's scratch spill.
__global__ void __launch_bounds__(256, 7) aggregate_kernel(
        const unsigned short* __restrict__ featb,
        const int* __restrict__ gbin, const int2* __restrict__ tbin,
        const int* __restrict__ gcount,
        unsigned short* __restrict__ zb) {
    __shared__ int   srcG[CAP];          // 3.2 KB geo sorted src
    __shared__ int   srcT[CAP];          // 3.2 KB trans sorted src
    __shared__ float wT[CAP];            // 3.2 KB trans sorted weights
    __shared__ int   kbG[KEYS + 1];      // 1.92 KB segment bounds
    __shared__ int   kbT[KEYS + 1];
    __shared__ int   histK[KEYS];
    __shared__ int   curK[KEYS];
    __shared__ int   wsA[4];
    __shared__ int   wpA[4];

    int bin = blockIdx.x;
    int node0 = bin * TILE;
    int nNodes = min(TILE, N_NODES - node0);
    int t = threadIdx.x, lane = t & 63, wave = t >> 6;   // 4 waves
    int g = wave * 8 + (lane >> 3);                      // group 0..31
    int co = (lane & 7) * 8;                             // column offset (8 bf16)

    int nEg = min(gcount[bin], CAP);
    int nEt = min(gcount[NBINS + bin], CAP);
    const int*  bpg = gbin + (size_t)bin * CAP;
    const int2* bpt = tbin + (size_t)bin * CAP;

    // ---- sort geo by (dloc*8 | src>>14) ----
    for (int i = t; i < KEYS; i += 256) histK[i] = 0;
    __syncthreads();
    for (int i = t; i < nEg; i += 256) {
        int p = bpg[i];
        atomicAdd(&histK[((p >> 20) << 3) | ((p & 0xFFFFF) >> 14)], 1);
    }
    __syncthreads();
    scan_keys(histK, kbG, curK, wsA, wpA, nEg, t, lane, wave);
    for (int i = t; i < nEg; i += 256) {
        int p = bpg[i];
        int key = ((p >> 20) << 3) | ((p & 0xFFFFF) >> 14);
        int pos = atomicAdd(&curK[key], 1);
        srcG[pos] = p & 0xFFFFF;
    }
    __syncthreads();

    // ---- sort trans (reuse histK/curK) ----
    for (int i = t; i < KEYS; i += 256) histK[i] = 0;
    __syncthreads();
    for (int i = t; i < nEt; i += 256) {
        int p = bpt[i].x;
        atomicAdd(&histK[((p >> 20) << 3) | ((p & 0xFFFFF) >> 14)], 1);
    }
    __syncthreads();
    scan_keys(histK, kbT, curK, wsA, wpA, nEt, t, lane, wave);
    for (int i = t; i < nEt; i += 256) {
        int2 p = bpt[i];
        int key = ((p.x >> 20) << 3) | ((p.x & 0xFFFFF) >> 14);
        int pos = atomicAdd(&curK[key], 1);
        srcT[pos] = p.x & 0xFFFFF;
        wT[pos]   = __int_as_float(p.y);
    }
    __syncthreads();

    // ---- chunk-outer gather, 2-way merged {geo,trans} per node ----
    float aGA[8] = {0.f,0.f,0.f,0.f,0.f,0.f,0.f,0.f};
    float aGB[8] = {0.f,0.f,0.f,0.f,0.f,0.f,0.f,0.f};
    float aTA[8] = {0.f,0.f,0.f,0.f,0.f,0.f,0.f,0.f};
    float aTB[8] = {0.f,0.f,0.f,0.f,0.f,0.f,0.f,0.f};
    int nA = g, nB = g + 32;
    bool actA = (nA < nNodes);
    bool hasB = (nB < nNodes);

    for (int c = 0; c < NCH; ++c) {
        // Node A: merge geo+trans segments (2 loads in flight per round).
        if (actA) {
            int kG = kbG[nA * NCH + c], eG = kbG[nA * NCH + c + 1];
            int kT = kbT[nA * NCH + c], eT = kbT[nA * NCH + c + 1];
            while ((kG < eG) | (kT < eT)) {
                bool a = kG < eG, b = kT < eT;
                int sG = srcG[a ? kG : 0];
                int sT = srcT[b ? kT : 0];
                float ga = a ? 1.0f : 0.0f;
                float wt = b ? wT[kT] : 0.0f;
                us8 rG = *(const us8*)&featb[(size_t)sG * DIM + co];
                us8 rT = *(const us8*)&featb[(size_t)sT * DIM + co];
                #pragma unroll
                for (int j = 0; j < 8; ++j) {
                    aGA[j] += bf2f(rG[j]) * ga;
                    aTA[j] += bf2f(rT[j]) * wt;
                }
                kG += a; kT += b;
            }
        }
        // Node B: same.
        if (hasB) {
            int kG = kbG[nB * NCH + c], eG = kbG[nB * NCH + c + 1];
            int kT = kbT[nB * NCH + c], eT = kbT[nB * NCH + c + 1];
            while ((kG < eG) | (kT < eT)) {
                bool a = kG < eG, b = kT < eT;
                int sG = srcG[a ? kG : 0];
                int sT = srcT[b ? kT : 0];
                float ga = a ? 1.0f : 0.0f;
                float wt = b ? wT[kT] : 0.0f;
                us8 rG = *(const us8*)&featb[(size_t)sG * DIM + co];
                us8 rT = *(const us8*)&featb[(size_t)sT * DIM + co];
                #pragma unroll
                for (int j = 0; j < 8; ++j) {
                    aGB[j] += bf2f(rG[j]) * ga;
                    aTB[j] += bf2f(rT[j]) * wt;
                }
                kG += a; kT += b;
            }
        }
    }

    // ---- write zb rows ----
    if (actA) {
        int degA = kbG[(nA + 1) * NCH] - kbG[nA * NCH];
        float sc = 1.0f / fmaxf((float)degA, 1.0f);          // geo -> mean
        us8 og, ot;
        #pragma unroll
        for (int j = 0; j < 8; ++j) { og[j] = f2bf(aGA[j] * sc); ot[j] = f2bf(aTA[j]); }
        *(us8*)&zb[(size_t)(node0 + nA) * DIM + co] = og;
        *(us8*)&zb[(size_t)(N_NODES + node0 + nA) * DIM + co] = ot;
    }
    if (hasB) {
        int degB = kbG[(nB + 1) * NCH] - kbG[nB * NCH];
        float sc = 1.0f / fmaxf((float)degB, 1.0f);
        us8 og, ot;
        #pragma unroll
        for (int j = 0; j < 8; ++j) { og[j] = f2bf(aGB[j] * sc); ot[j] = f2bf(aTB[j]); }
        *(us8*)&zb[(size_t)(node0 + nB) * DIM + co] = og;
        *(us8*)&zb[(size_t)(N_NODES + node0 + nB) * DIM + co] = ot;
    }
}

// ---------- Semantic-attention MLP via bf16 MFMA; A-frags loaded directly from zb ----
__global__ void __launch_bounds__(256) mlp_mfma_kernel(
        const unsigned short* __restrict__ zb,
        const unsigned short* __restrict__ W1p,
        const float* __restrict__ bias1, const float* __restrict__ W2,
        float* __restrict__ partials) {
    __shared__ float wred[4][2];
    int t = threadIdx.x, lane = t & 63, wave = t >> 6;
    int m = lane & 15, q = lane >> 4;
    int base = blockIdx.x * 64 + wave * 16;
    int R = base + m;

    const unsigned short* rowp = zb + (size_t)R * DIM;
    short8 a0 = *(const short8*)(rowp + q * 8);          // k = q*8..q*8+7
    short8 a1 = *(const short8*)(rowp + 32 + q * 8);     // k = 32+q*8..

    float c0 = 0.0f, c1 = 0.0f;
    const short8* W1v = (const short8*)W1p;   // 2048 frags of 8 bf16

    #pragma unroll 4
    for (int n = 0; n < 16; ++n) {
        short8 b0 = W1v[(n * 2 + 0) * 64 + lane];
        short8 bK = W1v[(n * 2 + 1) * 64 + lane];
        f32x4 acc = {0.0f, 0.0f, 0.0f, 0.0f};
        acc = __builtin_amdgcn_mfma_f32_16x16x32_bf16(a0, b0, acc, 0, 0, 0);
        acc = __builtin_amdgcn_mfma_f32_16x16x32_bf16(a1, bK, acc, 0, 0, 0);
        int col = 16 * n + m;                 // C/D: col=lane&15, row=q*4+reg
        float bj = bias1[col];
        float w2 = W2[col];
        #pragma unroll
        for (int reg = 0; reg < 4; ++reg) {
            int Rr = base + q * 4 + reg;
            float h = tanh_fast(acc[reg] + bj);
            float contrib = h * w2;
            if (Rr < N_NODES) c0 += contrib; else c1 += contrib;
        }
    }

    #pragma unroll
    for (int off = 32; off > 0; off >>= 1) {
        c0 += __shfl_down(c0, off);
        c1 += __shfl_down(c1, off);
    }
    if (lane == 0) { wred[wave][0] = c0; wred[wave][1] = c1; }
    __syncthreads();
    if (t == 0) {
        partials[blockIdx.x * 2 + 0] = wred[0][0] + wred[1][0] + wred[2][0] + wred[3][0];
        partials[blockIdx.x * 2 + 1] = wred[0][1] + wred[1][1] + wred[2][1] + wred[3][1];
    }
}

// ---------- combine (+ fused beta): out = beta0*geo_mean + beta1*trans ----------
__global__ void __launch_bounds__(256) combine_kernel(
        const unsigned short* __restrict__ zb,
        const float* __restrict__ partials,
        float* __restrict__ out) {
    __shared__ float wred[4][2];
    __shared__ float bS[2];
    int t = threadIdx.x, lane = t & 63, wv = t >> 6;

    // Redundant per-block beta reduction (partials are L2-resident, 25 KB).
    float c0 = 0.0f, c1 = 0.0f;
    for (int i = t; i < MLP_ROWBLOCKS; i += 256) {
        c0 += partials[i * 2 + 0];
        c1 += partials[i * 2 + 1];
    }
    #pragma unroll
    for (int off = 32; off > 0; off >>= 1) {
        c0 += __shfl_down(c0, off);
        c1 += __shfl_down(c1, off);
    }
    if (lane == 0) { wred[wv][0] = c0; wred[wv][1] = c1; }
    __syncthreads();
    if (t == 0) {
        float s0 = (wred[0][0] + wred[1][0] + wred[2][0] + wred[3][0]) / (float)N_NODES;
        float s1 = (wred[0][1] + wred[1][1] + wred[2][1] + wred[3][1]) / (float)N_NODES;
        float m = fmaxf(s0, s1);
        float e0 = __expf(s0 - m), e1 = __expf(s1 - m);
        float inv = 1.0f / (e0 + e1);
        bS[0] = e0 * inv;
        bS[1] = e1 * inv;
    }
    __syncthreads();
    float b0 = bS[0];
    float b1 = bS[1];

    int gid = blockIdx.x * 256 + t;             // 8 elements per thread
    uint4 g = *(const uint4*)&zb[(size_t)gid * 8];
    uint4 tr = *(const uint4*)&zb[(size_t)N_NODES * DIM + (size_t)gid * 8];
    float4 o0, o1;
    o0.x = b0 * __uint_as_float(g.x << 16) + b1 * __uint_as_float(tr.x << 16);
    o0.y = b0 * __uint_as_float(g.x & 0xFFFF0000u) + b1 * __uint_as_float(tr.x & 0xFFFF0000u);
    o0.z = b0 * __uint_as_float(g.y << 16) + b1 * __uint_as_float(tr.y << 16);
    o0.w = b0 * __uint_as_float(g.y & 0xFFFF0000u) + b1 * __uint_as_float(tr.y & 0xFFFF0000u);
    o1.x = b0 * __uint_as_float(g.z << 16) + b1 * __uint_as_float(tr.z << 16);
    o1.y = b0 * __uint_as_float(g.z & 0xFFFF0000u) + b1 * __uint_as_float(tr.z & 0xFFFF0000u);
    o1.z = b0 * __uint_as_float(g.w << 16) + b1 * __uint_as_float(tr.w << 16);
    o1.w = b0 * __uint_as_float(g.w & 0xFFFF0000u) + b1 * __uint_as_float(tr.w & 0xFFFF0000u);
    *(float4*)&out[(size_t)gid * 8] = o0;
    *(float4*)&out[(size_t)gid * 8 + 4] = o1;
}

extern "C" void kernel_launch(void* const* d_in, const int* in_sizes, int n_in,
                              void* d_out, int out_size, void* d_ws, size_t ws_size,
                              hipStream_t stream) {
    const float* loc_feat = (const float*)d_in[0];
    const int* geo_src    = (const int*)d_in[1];
    const int* geo_dst    = (const int*)d_in[2];
    const int* trans_src  = (const int*)d_in[3];
    const int* trans_dst  = (const int*)d_in[4];
    const float* trans_w  = (const float*)d_in[5];
    const float* W1       = (const float*)d_in[6];
    const float* b1       = (const float*)d_in[7];
    const float* W2       = (const float*)d_in[8];
    float* out = (float*)d_out;

    // ws layout (4B units): [gcount 2*NBINS][gbin NBINS*CAP int][tbin NBINS*CAP int2]
    //   [partials 2*3125][beta 2 (unused)][W1p 16384 u16][featb N*64 u16][zb 2N*64 u16]
    int*   gcount   = (int*)d_ws;
    int*   gbin     = gcount + 2 * NBINS;
    int2*  tbin     = (int2*)(gbin + (size_t)NBINS * CAP);
    float* partials = (float*)(tbin + (size_t)NBINS * CAP);
    float* beta     = partials + 2 * MLP_ROWBLOCKS;
    unsigned short* W1p   = (unsigned short*)(beta + 2);
    unsigned short* featb = W1p + 16384;
    unsigned short* zb    = featb + (size_t)N_NODES * DIM;

    hipMemsetAsync(gcount, 0, 2 * NBINS * sizeof(int), stream);

    prep_kernel<<<PREP_BLOCKS, 512, 0, stream>>>(geo_src, geo_dst, trans_src,
                                                 trans_dst, trans_w,
                                                 gcount, gbin, tbin,
                                                 loc_feat, featb, W1, W1p);
    aggregate_kernel<<<NBINS, 256, 0, stream>>>(featb, gbin, tbin, gcount, zb);
    mlp_mfma_kernel<<<MLP_ROWBLOCKS, 256, 0, stream>>>(zb, W1p, b1, W2, partials);
    combine_kernel<<<(N_NODES * DIM / 8) / 256, 256, 0, stream>>>(zb, partials, out);
}